// Round 16
// baseline (144.557 us; speedup 1.0000x reference)
//
#include <hip/hip_runtime.h>
#include <math.h>

typedef int i32x4 __attribute__((ext_vector_type(4)));
typedef unsigned long long u64;

constexpr int TT = 4;
constexpr int BB = 32;
constexpr int CC = 384;
constexpr int NN = 256;
constexpr int HEADS = 8;
constexpr int HD = 48;
constexpr int BCN = BB * CC * NN;
constexpr int TBCN = TT * BCN;          // 12,582,912
constexpr int CCC = CC * CC;            // 147,456
constexpr int SROW = 400;               // padded S row: word stride 100 (odd*4)
constexpr int RROW = 68;                // padded repack row: word stride 17 (odd)
constexpr float MARGIN = 1e-4f;         // LIF margin triggering np-exact recompute
constexpr unsigned FCAP = 262144;       // flag list capacity

// exact: round_f32(N * 2^-23) == round_f32(N) * 2^-23 (scaling by exact pow2
// commutes with rounding) -- bit-identical to the fp64 path, 2 VALU ops.
__device__ inline float recomb(int a0, int a1, int a2) {
    int N = a0 + (a1 << 8) + (a2 << 16);
    return (float)N * 0x1p-23f;
}

// ---------------------------------------------------------------------------
// Kernel 0: quantize fp32 weights -> 3 signed-i8 digit planes of round(w*2^23)
// ---------------------------------------------------------------------------
__global__ __launch_bounds__(256) void k_wsplit(
    const float* __restrict__ qw, const float* __restrict__ kw,
    const float* __restrict__ vw, const float* __restrict__ pw,
    signed char* __restrict__ wq, unsigned* __restrict__ cnt) {
    if (blockIdx.x == 0 && threadIdx.x == 0) *cnt = 0u;
    int idx = blockIdx.x * 256 + threadIdx.x;     // 4*CCC total
    int mat = idx / CCC, r = idx % CCC;
    const float* src = (mat == 0) ? qw : (mat == 1) ? kw : (mat == 2) ? vw : pw;
    double w = (double)src[r];
    long long W = llround(w * 8388608.0);         // w * 2^23
    signed char d0 = (signed char)(W & 0xff); W = (W - d0) >> 8;
    signed char d1 = (signed char)(W & 0xff); W = (W - d1) >> 8;
    signed char d2 = (signed char)W;
    size_t base = (size_t)mat * 3 * CCC;
    wq[base + 0 * CCC + r] = d0;
    wq[base + 1 * CCC + r] = d1;
    wq[base + 2 * CCC + r] = d2;
}

// ---------------------------------------------------------------------------
// Kernel 1: shortcut LIF on x [t,b,c,n] -> u8 spikes xs in [t,b,n,c]
// ---------------------------------------------------------------------------
__global__ __launch_bounds__(256) void k_lif_x(const float* __restrict__ x,
                                               unsigned char* __restrict__ xs) {
    __shared__ unsigned char sL[4][64][68];
    const int b_ = blockIdx.x, c0 = blockIdx.y * 64, n0 = blockIdx.z * 64;
    const int tid = threadIdx.x;

    float vm[4][4];
#pragma unroll
    for (int a = 0; a < 4; ++a)
#pragma unroll
        for (int j = 0; j < 4; ++j) vm[a][j] = 0.f;

#pragma unroll
    for (int t = 0; t < TT; ++t) {
#pragma unroll
        for (int a = 0; a < 4; ++a) {
            int idx = tid + 256 * a;
            int ci = idx >> 4, nj4 = idx & 15;
            float4 xv = *(const float4*)&x[((size_t)((t * BB + b_) * CC) + c0 + ci) * NN + n0 + nj4 * 4];
            float xa[4] = {xv.x, xv.y, xv.z, xv.w};
#pragma unroll
            for (int j = 0; j < 4; ++j) {
                vm[a][j] = __fadd_rn(vm[a][j], __fmul_rn(__fsub_rn(xa[j], vm[a][j]), 0.5f));
                int s = (vm[a][j] >= 0.5f);
                sL[t][nj4 * 4 + j][ci] = (unsigned char)s;
                if (s) vm[a][j] = 0.f;
            }
        }
    }
    __syncthreads();
#pragma unroll
    for (int i = 0; i < 16; ++i) {
        int s = tid + 256 * i;
        int c4 = s & 15, n = (s >> 4) & 63, t = s >> 10;
        *(uchar4*)&xs[((size_t)((t * BB + b_) * NN) + n0 + n) * CC + c0 + c4 * 4] =
            *(const uchar4*)&sL[t][n][c4 * 4];
    }
}

// ---------------------------------------------------------------------------
// Kernel 2: FUSED q/k/v branch GEMM, MAT-MERGED: one block stages the S tile
// once and runs all 3 mats' K-loops + epilogues against it (3x MFMA per
// staging -> higher matrix-pipe duty cycle). W direct from global.
// Grid (B, 6, 8): ob = by*64, nb = bz*32. LDS 59.9KB -> 2 blocks/CU.
// ---------------------------------------------------------------------------
__global__ __launch_bounds__(256, 2) void k_branch_i8(
    const unsigned char* __restrict__ xs, const signed char* __restrict__ wq0,
    const float* __restrict__ qg, const float* __restrict__ qb,
    const float* __restrict__ qm, const float* __restrict__ qv,
    const float* __restrict__ kg_, const float* __restrict__ kb_,
    const float* __restrict__ km_, const float* __restrict__ kv_,
    const float* __restrict__ vg, const float* __restrict__ vb,
    const float* __restrict__ vm_, const float* __restrict__ vv_,
    unsigned char* __restrict__ qs, unsigned char* __restrict__ ks,
    unsigned char* __restrict__ vs,
    unsigned* __restrict__ cnt, unsigned* __restrict__ list) {
    __shared__ unsigned char S[4][32][SROW];   // 51,200 B, live whole kernel
    __shared__ unsigned char R[4][32][RROW];   //  8,704 B, reused per mat
    const int b_ = blockIdx.x;
    const int ob = blockIdx.y * 64, nb = blockIdx.z * 32;
    const int tid = threadIdx.x, lane = tid & 63, w = tid >> 6;
    const int lo16 = lane & 15, hi4 = lane >> 4;

    // ---- stage full-K S tile ONCE (pow2 map): 128 rows x 24 slots of 16B ----
    {
        const int sl3 = tid & 7;
#pragma unroll
        for (int i = 0; i < 4; ++i) {
            int row = i * 32 + (tid >> 3);             // t = row>>5, n = row&31
            const unsigned char* src =
                &xs[((size_t)(((row >> 5) * BB + b_) * NN) + nb + (row & 31)) * CC];
            unsigned char* dst = &S[0][0][0] + row * SROW;
#pragma unroll
            for (int j = 0; j < 3; ++j) {
                int so = (sl3 + 8 * j) * 16;
                *(i32x4*)(dst + so) = *(const i32x4*)(src + so);
            }
        }
    }
    __syncthreads();

    const unsigned char* sbase = &S[0][lo16][hi4 * 16];

    for (int mat = 0; mat < 3; ++mat) {
        const signed char* wq = wq0 + (size_t)mat * 3 * CCC;
        const float* gg  = (mat == 0) ? qg : (mat == 1) ? kg_ : vg;
        const float* bbp = (mat == 0) ? qb : (mat == 1) ? kb_ : vb;
        const float* mmp = (mat == 0) ? qm : (mat == 1) ? km_ : vm_;
        const float* vvp = (mat == 0) ? qv : (mat == 1) ? kv_ : vv_;
        unsigned char* spk = (mat == 0) ? qs : (mat == 1) ? ks : vs;

        i32x4 acc[3][4][2];
#pragma unroll
        for (int p = 0; p < 3; ++p)
#pragma unroll
            for (int t = 0; t < 4; ++t)
#pragma unroll
                for (int nf = 0; nf < 2; ++nf) acc[p][t][nf] = (i32x4){0, 0, 0, 0};

        // per-wave W pointer (rows w*16+lo16 exclusive to this wave)
        const signed char* wptr = wq + (size_t)(ob + w * 16 + lo16) * CC + hi4 * 16;
        i32x4 aw0 = *(const i32x4*)&wptr[0 * CCC];
        i32x4 aw1 = *(const i32x4*)&wptr[1 * CCC];
        i32x4 aw2 = *(const i32x4*)&wptr[2 * CCC];

#pragma unroll
        for (int s = 0; s < 6; ++s) {
            i32x4 nw0, nw1, nw2;
            if (s < 5) {                           // prefetch next K-step's W
                nw0 = *(const i32x4*)&wptr[0 * CCC + (s + 1) * 64];
                nw1 = *(const i32x4*)&wptr[1 * CCC + (s + 1) * 64];
                nw2 = *(const i32x4*)&wptr[2 * CCC + (s + 1) * 64];
            }
            __builtin_amdgcn_s_setprio(1);
#pragma unroll
            for (int t = 0; t < 4; ++t)
#pragma unroll
                for (int nf = 0; nf < 2; ++nf) {
                    i32x4 bfr = *(const i32x4*)&sbase[(t * 32 + nf * 16) * SROW + s * 64];
                    acc[0][t][nf] = __builtin_amdgcn_mfma_i32_16x16x64_i8(aw0, bfr, acc[0][t][nf], 0, 0, 0);
                    acc[1][t][nf] = __builtin_amdgcn_mfma_i32_16x16x64_i8(aw1, bfr, acc[1][t][nf], 0, 0, 0);
                    acc[2][t][nf] = __builtin_amdgcn_mfma_i32_16x16x64_i8(aw2, bfr, acc[2][t][nf], 0, 0, 0);
                }
            __builtin_amdgcn_s_setprio(0);
            if (s < 5) { aw0 = nw0; aw1 = nw1; aw2 = nw2; }
        }

        __syncthreads();   // prior mat's repack reads of R complete (K-loop gave slack)

        // epilogue: fp32 np-order BN + LIF, margin flagging, spikes into R
#pragma unroll
        for (int r = 0; r < 4; ++r) {
            const int o = ob + w * 16 + hi4 * 4 + r;
            const float inv = __fdiv_rn(gg[o], __fsqrt_rn(__fadd_rn(vvp[o], 1e-5f)));
            const float mu = mmp[o], be = bbp[o];
#pragma unroll
            for (int nf = 0; nf < 2; ++nf) {
                float vmem = 0.f, mg = 1e9f;
#pragma unroll
                for (int t = 0; t < 4; ++t) {
                    float dotf = recomb(acc[0][t][nf][r], acc[1][t][nf][r], acc[2][t][nf][r]);
                    float y = __fadd_rn(__fmul_rn(__fsub_rn(dotf, mu), inv), be);
                    vmem = __fadd_rn(vmem, __fmul_rn(__fsub_rn(y, vmem), 0.5f));
                    mg = fminf(mg, fabsf(__fsub_rn(vmem, 0.5f)));
                    int s = (vmem >= 0.5f);
                    R[t][nf * 16 + lo16][w * 16 + hi4 * 4 + r] = (unsigned char)s;
                    if (s) vmem = 0.f;
                }
                if (mg < MARGIN) {
                    unsigned idx = atomicAdd(cnt, 1u);
                    int n = nb + nf * 16 + lo16;
                    if (idx < FCAP) list[idx] = ((unsigned)mat << 22) | ((unsigned)b_ << 17) |
                                                ((unsigned)o << 8) | (unsigned)n;
                }
            }
        }
        __syncthreads();
#pragma unroll
        for (int i = 0; i < 8; ++i) {
            int e = tid + 256 * i;
            int c4 = e & 15, n = (e >> 4) & 31, t = e >> 9;
            *(uchar4*)&spk[((size_t)((t * BB + b_) * NN) + nb + n) * CC + ob + c4 * 4] =
                *(const uchar4*)&R[t][n][c4 * 4];
        }
    }
}

// ---------------------------------------------------------------------------
// Kernel 2b: np-exact fixup of flagged trajectories (block per item).
// ---------------------------------------------------------------------------
__global__ __launch_bounds__(256) void k_fixup(
    const unsigned char* __restrict__ xs,
    const float* __restrict__ qw, const float* __restrict__ kw, const float* __restrict__ vw,
    const float* __restrict__ qg, const float* __restrict__ qb,
    const float* __restrict__ qm, const float* __restrict__ qv,
    const float* __restrict__ kg_, const float* __restrict__ kb_,
    const float* __restrict__ km_, const float* __restrict__ kv_,
    const float* __restrict__ vg, const float* __restrict__ vb,
    const float* __restrict__ vm_, const float* __restrict__ vv_,
    unsigned char* __restrict__ qs, unsigned char* __restrict__ ks,
    unsigned char* __restrict__ vs,
    const unsigned* __restrict__ cnt, const unsigned* __restrict__ list) {
    __shared__ __align__(16) float sw[CC];
    __shared__ __align__(16) unsigned char sx[TT][CC];
    __shared__ float dots[TT];
    unsigned nfl = *cnt;
    if (nfl > FCAP) nfl = FCAP;
    for (unsigned i = blockIdx.x; i < nfl; i += gridDim.x) {
        unsigned e = list[i];
        int mat = e >> 22, b_ = (e >> 17) & 31, o = (e >> 8) & 511, n = e & 255;
        const float* wbase = (mat == 0) ? qw : (mat == 1) ? kw : vw;
        const float* wrow = wbase + (size_t)o * CC;
        for (int c = threadIdx.x; c < CC; c += 256) sw[c] = wrow[c];
        if (threadIdx.x < TT * (CC / 8)) {
            int t = threadIdx.x / (CC / 8), q = threadIdx.x % (CC / 8);
            *(u64*)&sx[t][q * 8] =
                *(const u64*)&xs[((size_t)((t * BB + b_) * NN) + n) * CC + q * 8];
        }
        __syncthreads();
        if (threadIdx.x < TT) {
            int t = threadIdx.x;
            float acc = 0.f;
            for (int c = 0; c < CC; ++c)
                acc = __fmaf_rn((float)sx[t][c], sw[c], acc);
            dots[t] = acc;
        }
        __syncthreads();
        if (threadIdx.x == 0) {
            const float* G = (mat == 0) ? qg : (mat == 1) ? kg_ : vg;
            const float* Bb = (mat == 0) ? qb : (mat == 1) ? kb_ : vb;
            const float* M = (mat == 0) ? qm : (mat == 1) ? km_ : vm_;
            const float* V = (mat == 0) ? qv : (mat == 1) ? kv_ : vv_;
            unsigned char* S = (mat == 0) ? qs : (mat == 1) ? ks : vs;
            const float inv = __fdiv_rn(G[o], __fsqrt_rn(__fadd_rn(V[o], 1e-5f)));
            const float mu = M[o], be = Bb[o];
            float vmem = 0.f;
            for (int t = 0; t < TT; ++t) {
                float y = __fadd_rn(__fmul_rn(__fsub_rn(dots[t], mu), inv), be);
                vmem = __fadd_rn(vmem, __fmul_rn(__fsub_rn(y, vmem), 0.5f));
                int s = (vmem >= 0.5f);
                S[((size_t)((t * BB + b_) * NN) + n) * CC + o] = (unsigned char)s;
                if (s) vmem = 0.f;
            }
        }
        __syncthreads();
    }
}

// ---------------------------------------------------------------------------
// Kernel 3: v spikes [t,b,n,c] u8 -> f32 out [t,b,h,n,d] (coalesced float4)
// ---------------------------------------------------------------------------
__global__ __launch_bounds__(256) void k_vout(const unsigned char* __restrict__ vs,
                                              float* __restrict__ vout) {
    int e = blockIdx.x * 256 + threadIdx.x;
    int d4 = e % 12;
    int r = e / 12;
    int n = r & 255;
    r >>= 8;
    int h = r & 7;
    int tb = r >> 3;
    uchar4 u = *(const uchar4*)&vs[((size_t)tb * NN + n) * CC + h * HD + d4 * 4];
    float4 o = {(float)u.x, (float)u.y, (float)u.z, (float)u.w};
    *(float4*)&vout[(((size_t)tb * HEADS + h) * NN + n) * HD + d4 * 4] = o;
}

// ---------------------------------------------------------------------------
// Kernel 4: kvsum[t,b,c] = sum_n k*v  (exact integer)
// ---------------------------------------------------------------------------
__global__ __launch_bounds__(256) void k_kvsum(const unsigned char* __restrict__ ks,
                                               const unsigned char* __restrict__ vs,
                                               int* __restrict__ kvsum) {
    __shared__ int P[5][CC];
    const int tb = blockIdx.x, tid = threadIdx.x;
    if (tid < 240) {
        int c8 = tid % 48, sl = tid / 48;
        int a[8] = {0, 0, 0, 0, 0, 0, 0, 0};
        for (int n = sl; n < NN; n += 5) {
            u64 kk = *(const u64*)&ks[((size_t)tb * NN + n) * CC + c8 * 8];
            u64 vvv = *(const u64*)&vs[((size_t)tb * NN + n) * CC + c8 * 8];
            u64 u = kk & vvv;
#pragma unroll
            for (int j = 0; j < 8; ++j) a[j] += (int)((u >> (8 * j)) & 1);
        }
#pragma unroll
        for (int j = 0; j < 8; ++j) P[sl][c8 * 8 + j] = a[j];
    }
    __syncthreads();
    for (int c = tid; c < CC; c += 256) {
        kvsum[(size_t)tb * CC + c] = P[0][c] + P[1][c] + P[2][c] + P[3][c] + P[4][c];
    }
}

// ---------------------------------------------------------------------------
// Kernel 5: talking heads + LIF, fp32 np-order
// ---------------------------------------------------------------------------
__global__ __launch_bounds__(384) void k_thlif(const int* __restrict__ kvsum,
                                               const float* __restrict__ th,
                                               unsigned char* __restrict__ kvm) {
    __shared__ int kv0[TT][CC];
    const int b_ = blockIdx.x, c = threadIdx.x;
#pragma unroll
    for (int t = 0; t < TT; ++t) kv0[t][c] = kvsum[(size_t)(t * BB + b_) * CC + c];
    __syncthreads();
    const int ho = c / HD, d = c % HD;
    float vmem = 0.f;
#pragma unroll
    for (int t = 0; t < TT; ++t) {
        float s = 0.f;
#pragma unroll
        for (int h = 0; h < HEADS; ++h)
            s = __fadd_rn(s, __fmul_rn(th[ho * HEADS + h], (float)kv0[t][h * HD + d]));
        vmem = __fadd_rn(vmem, __fmul_rn(__fsub_rn(s, vmem), 0.5f));
        int sp = (vmem >= 0.5f);
        kvm[(size_t)(t * BB + b_) * CC + c] = (unsigned char)sp;
        if (sp) vmem = 0.f;
    }
}

// ---------------------------------------------------------------------------
// Kernel 6: proj GEMM (pow2 staging + setprio); fp32 np-order epilogue:
// +bias, BN, +identity -> f32 out [t,b,c,n]  (real-valued; no decisions)
// ---------------------------------------------------------------------------
__global__ __launch_bounds__(256, 3) void k_proj_i8(
    const unsigned char* __restrict__ qs, const unsigned char* __restrict__ kvm,
    const signed char* __restrict__ wq, const float* __restrict__ pbias,
    const float* __restrict__ gg, const float* __restrict__ bbp,
    const float* __restrict__ mmp, const float* __restrict__ vvp,
    const float* __restrict__ xin, float* __restrict__ out) {
    __shared__ unsigned char S[4][32][SROW];
    const int b_ = blockIdx.x, ob = blockIdx.y * 64, nb = blockIdx.z * 32;
    const int tid = threadIdx.x, lane = tid & 63, w = tid >> 6;
    const int lo16 = lane & 15, hi4 = lane >> 4;

    // stage full-K (q & kvmask) tile once (pow2 map)
    {
        const int sl3 = tid & 7;
#pragma unroll
        for (int i = 0; i < 4; ++i) {
            int row = i * 32 + (tid >> 3);             // t = row>>5, n = row&31
            int t = row >> 5, n = row & 31;
            const unsigned char* srcq = &qs[((size_t)((t * BB + b_) * NN) + nb + n) * CC];
            const unsigned char* srcm = &kvm[(size_t)((t * BB + b_) * CC)];
            unsigned char* dst = &S[0][0][0] + row * SROW;
#pragma unroll
            for (int j = 0; j < 3; ++j) {
                int so = (sl3 + 8 * j) * 16;
                i32x4 qv = *(const i32x4*)(srcq + so);
                i32x4 mv = *(const i32x4*)(srcm + so);
                *(i32x4*)(dst + so) = qv & mv;
            }
        }
    }
    __syncthreads();

    i32x4 acc[3][4][2];
#pragma unroll
    for (int p = 0; p < 3; ++p)
#pragma unroll
        for (int t = 0; t < 4; ++t)
#pragma unroll
            for (int nf = 0; nf < 2; ++nf) acc[p][t][nf] = (i32x4){0, 0, 0, 0};

    const signed char* wptr = wq + (size_t)(ob + w * 16 + lo16) * CC + hi4 * 16;
    const unsigned char* sbase = &S[0][lo16][hi4 * 16];
    i32x4 aw0 = *(const i32x4*)&wptr[0 * CCC];
    i32x4 aw1 = *(const i32x4*)&wptr[1 * CCC];
    i32x4 aw2 = *(const i32x4*)&wptr[2 * CCC];

#pragma unroll
    for (int s = 0; s < 6; ++s) {
        i32x4 nw0, nw1, nw2;
        if (s < 5) {
            nw0 = *(const i32x4*)&wptr[0 * CCC + (s + 1) * 64];
            nw1 = *(const i32x4*)&wptr[1 * CCC + (s + 1) * 64];
            nw2 = *(const i32x4*)&wptr[2 * CCC + (s + 1) * 64];
        }
        __builtin_amdgcn_s_setprio(1);
#pragma unroll
        for (int t = 0; t < 4; ++t)
#pragma unroll
            for (int nf = 0; nf < 2; ++nf) {
                i32x4 bfr = *(const i32x4*)&sbase[(t * 32 + nf * 16) * SROW + s * 64];
                acc[0][t][nf] = __builtin_amdgcn_mfma_i32_16x16x64_i8(aw0, bfr, acc[0][t][nf], 0, 0, 0);
                acc[1][t][nf] = __builtin_amdgcn_mfma_i32_16x16x64_i8(aw1, bfr, acc[1][t][nf], 0, 0, 0);
                acc[2][t][nf] = __builtin_amdgcn_mfma_i32_16x16x64_i8(aw2, bfr, acc[2][t][nf], 0, 0, 0);
            }
        __builtin_amdgcn_s_setprio(0);
        if (s < 5) { aw0 = nw0; aw1 = nw1; aw2 = nw2; }
    }

#pragma unroll
    for (int r = 0; r < 4; ++r) {
        const int o = ob + w * 16 + hi4 * 4 + r;
        const float inv = __fdiv_rn(gg[o], __fsqrt_rn(__fadd_rn(vvp[o], 1e-5f)));
        const float mu = mmp[o], be = bbp[o], pb = pbias[o];
#pragma unroll
        for (int nf = 0; nf < 2; ++nf) {
#pragma unroll
            for (int t = 0; t < 4; ++t) {
                float dotf = recomb(acc[0][t][nf][r], acc[1][t][nf][r], acc[2][t][nf][r]);
                size_t idx = ((size_t)((t * BB + b_) * CC) + o) * NN + nb + nf * 16 + lo16;
                float y = __fadd_rn(__fmul_rn(__fsub_rn(__fadd_rn(dotf, pb), mu), inv), be);
                out[idx] = __fadd_rn(y, xin[idx]);
            }
        }
    }
}

// ---------------------------------------------------------------------------
extern "C" void kernel_launch(void* const* d_in, const int* in_sizes, int n_in,
                              void* d_out, int out_size, void* d_ws, size_t ws_size,
                              hipStream_t stream) {
    const float* x    = (const float*)d_in[0];
    const float* q_w  = (const float*)d_in[1];
    const float* k_w  = (const float*)d_in[2];
    const float* v_w  = (const float*)d_in[3];
    const float* q_g  = (const float*)d_in[4];
    const float* q_b  = (const float*)d_in[5];
    const float* q_m  = (const float*)d_in[6];
    const float* q_v  = (const float*)d_in[7];
    const float* k_g  = (const float*)d_in[8];
    const float* k_b  = (const float*)d_in[9];
    const float* k_m  = (const float*)d_in[10];
    const float* k_v  = (const float*)d_in[11];
    const float* v_g  = (const float*)d_in[12];
    const float* v_b  = (const float*)d_in[13];
    const float* v_m  = (const float*)d_in[14];
    const float* v_v  = (const float*)d_in[15];
    const float* p_g  = (const float*)d_in[16];
    const float* p_b  = (const float*)d_in[17];
    const float* p_m  = (const float*)d_in[18];
    const float* p_v  = (const float*)d_in[19];
    const float* th_w = (const float*)d_in[20];
    const float* pr_w = (const float*)d_in[21];
    const float* pr_b = (const float*)d_in[22];

    float* out  = (float*)d_out;
    float* vout = out + (size_t)TBCN;

    unsigned char* ws  = (unsigned char*)d_ws;
    unsigned char* xs  = ws;
    unsigned char* qs  = ws + (size_t)TBCN;
    unsigned char* ks2 = ws + (size_t)2 * TBCN;
    unsigned char* vs2 = ws + (size_t)3 * TBCN;
    signed char* wq    = (signed char*)(ws + (size_t)4 * TBCN);          // 4 mats * 3*CCC
    int* kvsum         = (int*)(ws + (size_t)4 * TBCN + 12ull * CCC);
    unsigned char* kvm = (unsigned char*)(kvsum + TT * BB * CC);
    unsigned* fcnt     = (unsigned*)(kvm + (size_t)TT * BB * CC + 64);
    unsigned* flist    = fcnt + 16;

    k_wsplit<<<(4 * CCC) / 256, 256, 0, stream>>>(q_w, k_w, v_w, pr_w, wq, fcnt);
    k_lif_x<<<dim3(BB, CC / 64, NN / 64), 256, 0, stream>>>(x, xs);

    // fused q/k/v branches, mat-merged: grid (B, 6 ob-tiles, 8 nb-tiles)
    k_branch_i8<<<dim3(BB, CC / 64, NN / 32), 256, 0, stream>>>(
        xs, wq,
        q_g, q_b, q_m, q_v,
        k_g, k_b, k_m, k_v,
        v_g, v_b, v_m, v_v,
        qs, ks2, vs2, fcnt, flist);

    k_fixup<<<2048, 256, 0, stream>>>(xs, q_w, k_w, v_w,
                                      q_g, q_b, q_m, q_v,
                                      k_g, k_b, k_m, k_v,
                                      v_g, v_b, v_m, v_v,
                                      qs, ks2, vs2, fcnt, flist);

    k_vout<<<(TBCN / 4) / 256, 256, 0, stream>>>(vs2, vout);
    k_kvsum<<<TT * BB, 256, 0, stream>>>(ks2, vs2, kvsum);
    k_thlif<<<BB, CC, 0, stream>>>(kvsum, th_w, kvm);

    k_proj_i8<<<dim3(BB, CC / 64, NN / 32), 256, 0, stream>>>(
        qs, kvm, wq + 3ull * 3 * CCC, pr_b,
        p_g, p_b, p_m, p_v, x, out);
}

// Round 17
// 138.364 us; speedup vs baseline: 1.0448x; 1.0448x over previous
//
#include <hip/hip_runtime.h>
#include <math.h>

typedef int i32x4 __attribute__((ext_vector_type(4)));
typedef unsigned long long u64;

constexpr int TT = 4;
constexpr int BB = 32;
constexpr int CC = 384;
constexpr int NN = 256;
constexpr int HEADS = 8;
constexpr int HD = 48;
constexpr int BCN = BB * CC * NN;
constexpr int TBCN = TT * BCN;          // 12,582,912
constexpr int CCC = CC * CC;            // 147,456
constexpr int SROW = 400;               // padded S row: word stride 100 (odd*4)
constexpr int RROW = 68;                // padded repack row: word stride 17 (odd)
constexpr float MARGIN = 1e-4f;         // LIF margin triggering np-exact recompute
constexpr unsigned FCAP = 262144;       // flag list capacity

// exact: round_f32(N * 2^-23) == round_f32(N) * 2^-23 (scaling by exact pow2
// commutes with rounding) -- bit-identical to the fp64 path, 2 VALU ops.
__device__ inline float recomb(int a0, int a1, int a2) {
    int N = a0 + (a1 << 8) + (a2 << 16);
    return (float)N * 0x1p-23f;
}
// proj path: 2-plane quant round(w*2^15); dot error <= 384*2^-16 = 5.9e-3,
// far under the 0.1075 threshold (proj feeds no spike decision).
__device__ inline float recomb2(int a0, int a1) {
    int N = a0 + (a1 << 8);
    return (float)N * 0x1p-15f;
}

// ---------------------------------------------------------------------------
// Kernel 0: quantize fp32 weights -> i8 digit planes.
// mats 0..2 (q/k/v): 3 planes of round(w*2^23)  (exact-recomb branch path)
// mat 3 (proj):      2 planes of round(w*2^15)  (plane 2 zeroed, unused)
// ---------------------------------------------------------------------------
__global__ __launch_bounds__(256) void k_wsplit(
    const float* __restrict__ qw, const float* __restrict__ kw,
    const float* __restrict__ vw, const float* __restrict__ pw,
    signed char* __restrict__ wq, unsigned* __restrict__ cnt) {
    if (blockIdx.x == 0 && threadIdx.x == 0) *cnt = 0u;
    int idx = blockIdx.x * 256 + threadIdx.x;     // 4*CCC total
    int mat = idx / CCC, r = idx % CCC;
    const float* src = (mat == 0) ? qw : (mat == 1) ? kw : (mat == 2) ? vw : pw;
    double w = (double)src[r];
    size_t base = (size_t)mat * 3 * CCC;
    if (mat < 3) {
        long long W = llround(w * 8388608.0);         // w * 2^23
        signed char d0 = (signed char)(W & 0xff); W = (W - d0) >> 8;
        signed char d1 = (signed char)(W & 0xff); W = (W - d1) >> 8;
        signed char d2 = (signed char)W;
        wq[base + 0 * CCC + r] = d0;
        wq[base + 1 * CCC + r] = d1;
        wq[base + 2 * CCC + r] = d2;
    } else {
        long long W = llround(w * 32768.0);           // w * 2^15
        signed char d0 = (signed char)(W & 0xff); W = (W - d0) >> 8;
        signed char d1 = (signed char)W;
        wq[base + 0 * CCC + r] = d0;
        wq[base + 1 * CCC + r] = d1;
        wq[base + 2 * CCC + r] = 0;
    }
}

// ---------------------------------------------------------------------------
// Kernel 1: shortcut LIF on x [t,b,c,n] -> u8 spikes xs in [t,b,n,c]
// ---------------------------------------------------------------------------
__global__ __launch_bounds__(256) void k_lif_x(const float* __restrict__ x,
                                               unsigned char* __restrict__ xs) {
    __shared__ unsigned char sL[4][64][68];
    const int b_ = blockIdx.x, c0 = blockIdx.y * 64, n0 = blockIdx.z * 64;
    const int tid = threadIdx.x;

    float vm[4][4];
#pragma unroll
    for (int a = 0; a < 4; ++a)
#pragma unroll
        for (int j = 0; j < 4; ++j) vm[a][j] = 0.f;

#pragma unroll
    for (int t = 0; t < TT; ++t) {
#pragma unroll
        for (int a = 0; a < 4; ++a) {
            int idx = tid + 256 * a;
            int ci = idx >> 4, nj4 = idx & 15;
            float4 xv = *(const float4*)&x[((size_t)((t * BB + b_) * CC) + c0 + ci) * NN + n0 + nj4 * 4];
            float xa[4] = {xv.x, xv.y, xv.z, xv.w};
#pragma unroll
            for (int j = 0; j < 4; ++j) {
                vm[a][j] = __fadd_rn(vm[a][j], __fmul_rn(__fsub_rn(xa[j], vm[a][j]), 0.5f));
                int s = (vm[a][j] >= 0.5f);
                sL[t][nj4 * 4 + j][ci] = (unsigned char)s;
                if (s) vm[a][j] = 0.f;
            }
        }
    }
    __syncthreads();
#pragma unroll
    for (int i = 0; i < 16; ++i) {
        int s = tid + 256 * i;
        int c4 = s & 15, n = (s >> 4) & 63, t = s >> 10;
        *(uchar4*)&xs[((size_t)((t * BB + b_) * NN) + n0 + n) * CC + c0 + c4 * 4] =
            *(const uchar4*)&sL[t][n][c4 * 4];
    }
}

// ---------------------------------------------------------------------------
// Kernel 2: FUSED q/k/v branch GEMM (round-15 form). Full-K S tile staged
// ONCE (pow2 map), W direct from global, setprio around MFMA, 3 blocks/CU.
// Grid (B, 3*6, 8): mat = by/6, ob = (by%6)*64, nb = bz*32.
// ---------------------------------------------------------------------------
__global__ __launch_bounds__(256, 3) void k_branch_i8(
    const unsigned char* __restrict__ xs, const signed char* __restrict__ wq0,
    const float* __restrict__ qg, const float* __restrict__ qb,
    const float* __restrict__ qm, const float* __restrict__ qv,
    const float* __restrict__ kg_, const float* __restrict__ kb_,
    const float* __restrict__ km_, const float* __restrict__ kv_,
    const float* __restrict__ vg, const float* __restrict__ vb,
    const float* __restrict__ vm_, const float* __restrict__ vv_,
    unsigned char* __restrict__ qs, unsigned char* __restrict__ ks,
    unsigned char* __restrict__ vs,
    unsigned* __restrict__ cnt, unsigned* __restrict__ list) {
    __shared__ union {
        unsigned char S[4][32][SROW];   // 51,200 B (live during K-loop)
        unsigned char R[4][32][RROW];   // repack (live after K-loop)
    } L;
    const int b_ = blockIdx.x;
    const int mat = blockIdx.y / 6, ob = (blockIdx.y % 6) * 64, nb = blockIdx.z * 32;
    const int tid = threadIdx.x, lane = tid & 63, w = tid >> 6;
    const int lo16 = lane & 15, hi4 = lane >> 4;

    const signed char* wq = wq0 + (size_t)mat * 3 * CCC;
    const float* gg  = (mat == 0) ? qg : (mat == 1) ? kg_ : vg;
    const float* bbp = (mat == 0) ? qb : (mat == 1) ? kb_ : vb;
    const float* mmp = (mat == 0) ? qm : (mat == 1) ? km_ : vm_;
    const float* vvp = (mat == 0) ? qv : (mat == 1) ? kv_ : vv_;
    unsigned char* spk = (mat == 0) ? qs : (mat == 1) ? ks : vs;

    // ---- stage full-K S tile once (pow2 map): 128 rows x 24 slots of 16B ----
    {
        const int sl3 = tid & 7;
#pragma unroll
        for (int i = 0; i < 4; ++i) {
            int row = i * 32 + (tid >> 3);             // t = row>>5, n = row&31
            const unsigned char* src =
                &xs[((size_t)(((row >> 5) * BB + b_) * NN) + nb + (row & 31)) * CC];
            unsigned char* dst = &L.S[0][0][0] + row * SROW;
#pragma unroll
            for (int j = 0; j < 3; ++j) {
                int so = (sl3 + 8 * j) * 16;
                *(i32x4*)(dst + so) = *(const i32x4*)(src + so);
            }
        }
    }
    __syncthreads();

    i32x4 acc[3][4][2];
#pragma unroll
    for (int p = 0; p < 3; ++p)
#pragma unroll
        for (int t = 0; t < 4; ++t)
#pragma unroll
            for (int nf = 0; nf < 2; ++nf) acc[p][t][nf] = (i32x4){0, 0, 0, 0};

    // per-wave W pointer (rows w*16+lo16 exclusive to this wave)
    const signed char* wptr = wq + (size_t)(ob + w * 16 + lo16) * CC + hi4 * 16;
    const unsigned char* sbase = &L.S[0][lo16][hi4 * 16];

    i32x4 aw0 = *(const i32x4*)&wptr[0 * CCC];
    i32x4 aw1 = *(const i32x4*)&wptr[1 * CCC];
    i32x4 aw2 = *(const i32x4*)&wptr[2 * CCC];

#pragma unroll
    for (int s = 0; s < 6; ++s) {
        i32x4 nw0, nw1, nw2;
        if (s < 5) {                           // prefetch next K-step's W
            nw0 = *(const i32x4*)&wptr[0 * CCC + (s + 1) * 64];
            nw1 = *(const i32x4*)&wptr[1 * CCC + (s + 1) * 64];
            nw2 = *(const i32x4*)&wptr[2 * CCC + (s + 1) * 64];
        }
        __builtin_amdgcn_s_setprio(1);
#pragma unroll
        for (int t = 0; t < 4; ++t)
#pragma unroll
            for (int nf = 0; nf < 2; ++nf) {
                i32x4 bfr = *(const i32x4*)&sbase[(t * 32 + nf * 16) * SROW + s * 64];
                acc[0][t][nf] = __builtin_amdgcn_mfma_i32_16x16x64_i8(aw0, bfr, acc[0][t][nf], 0, 0, 0);
                acc[1][t][nf] = __builtin_amdgcn_mfma_i32_16x16x64_i8(aw1, bfr, acc[1][t][nf], 0, 0, 0);
                acc[2][t][nf] = __builtin_amdgcn_mfma_i32_16x16x64_i8(aw2, bfr, acc[2][t][nf], 0, 0, 0);
            }
        __builtin_amdgcn_s_setprio(0);
        if (s < 5) { aw0 = nw0; aw1 = nw1; aw2 = nw2; }
    }
    __syncthreads();   // S dead everywhere before R overlay

    // epilogue: fp32 np-order BN + LIF, margin flagging, spikes into LDS repack
#pragma unroll
    for (int r = 0; r < 4; ++r) {
        const int o = ob + w * 16 + hi4 * 4 + r;
        const float inv = __fdiv_rn(gg[o], __fsqrt_rn(__fadd_rn(vvp[o], 1e-5f)));
        const float mu = mmp[o], be = bbp[o];
#pragma unroll
        for (int nf = 0; nf < 2; ++nf) {
            float vmem = 0.f, mg = 1e9f;
#pragma unroll
            for (int t = 0; t < 4; ++t) {
                float dotf = recomb(acc[0][t][nf][r], acc[1][t][nf][r], acc[2][t][nf][r]);
                float y = __fadd_rn(__fmul_rn(__fsub_rn(dotf, mu), inv), be);
                vmem = __fadd_rn(vmem, __fmul_rn(__fsub_rn(y, vmem), 0.5f));
                mg = fminf(mg, fabsf(__fsub_rn(vmem, 0.5f)));
                int s = (vmem >= 0.5f);
                L.R[t][nf * 16 + lo16][w * 16 + hi4 * 4 + r] = (unsigned char)s;
                if (s) vmem = 0.f;
            }
            if (mg < MARGIN) {
                unsigned idx = atomicAdd(cnt, 1u);
                int n = nb + nf * 16 + lo16;
                if (idx < FCAP) list[idx] = ((unsigned)mat << 22) | ((unsigned)b_ << 17) |
                                            ((unsigned)o << 8) | (unsigned)n;
            }
        }
    }
    __syncthreads();
#pragma unroll
    for (int i = 0; i < 8; ++i) {
        int e = tid + 256 * i;
        int c4 = e & 15, n = (e >> 4) & 31, t = e >> 9;
        *(uchar4*)&spk[((size_t)((t * BB + b_) * NN) + nb + n) * CC + ob + c4 * 4] =
            *(const uchar4*)&L.R[t][n][c4 * 4];
    }
}

// ---------------------------------------------------------------------------
// Kernel 2b: np-exact fixup of flagged trajectories (block per item).
// ---------------------------------------------------------------------------
__global__ __launch_bounds__(256) void k_fixup(
    const unsigned char* __restrict__ xs,
    const float* __restrict__ qw, const float* __restrict__ kw, const float* __restrict__ vw,
    const float* __restrict__ qg, const float* __restrict__ qb,
    const float* __restrict__ qm, const float* __restrict__ qv,
    const float* __restrict__ kg_, const float* __restrict__ kb_,
    const float* __restrict__ km_, const float* __restrict__ kv_,
    const float* __restrict__ vg, const float* __restrict__ vb,
    const float* __restrict__ vm_, const float* __restrict__ vv_,
    unsigned char* __restrict__ qs, unsigned char* __restrict__ ks,
    unsigned char* __restrict__ vs,
    const unsigned* __restrict__ cnt, const unsigned* __restrict__ list) {
    __shared__ __align__(16) float sw[CC];
    __shared__ __align__(16) unsigned char sx[TT][CC];
    __shared__ float dots[TT];
    unsigned nfl = *cnt;
    if (nfl > FCAP) nfl = FCAP;
    for (unsigned i = blockIdx.x; i < nfl; i += gridDim.x) {
        unsigned e = list[i];
        int mat = e >> 22, b_ = (e >> 17) & 31, o = (e >> 8) & 511, n = e & 255;
        const float* wbase = (mat == 0) ? qw : (mat == 1) ? kw : vw;
        const float* wrow = wbase + (size_t)o * CC;
        for (int c = threadIdx.x; c < CC; c += 256) sw[c] = wrow[c];
        if (threadIdx.x < TT * (CC / 8)) {
            int t = threadIdx.x / (CC / 8), q = threadIdx.x % (CC / 8);
            *(u64*)&sx[t][q * 8] =
                *(const u64*)&xs[((size_t)((t * BB + b_) * NN) + n) * CC + q * 8];
        }
        __syncthreads();
        if (threadIdx.x < TT) {
            int t = threadIdx.x;
            float acc = 0.f;
            for (int c = 0; c < CC; ++c)
                acc = __fmaf_rn((float)sx[t][c], sw[c], acc);
            dots[t] = acc;
        }
        __syncthreads();
        if (threadIdx.x == 0) {
            const float* G = (mat == 0) ? qg : (mat == 1) ? kg_ : vg;
            const float* Bb = (mat == 0) ? qb : (mat == 1) ? kb_ : vb;
            const float* M = (mat == 0) ? qm : (mat == 1) ? km_ : vm_;
            const float* V = (mat == 0) ? qv : (mat == 1) ? kv_ : vv_;
            unsigned char* S = (mat == 0) ? qs : (mat == 1) ? ks : vs;
            const float inv = __fdiv_rn(G[o], __fsqrt_rn(__fadd_rn(V[o], 1e-5f)));
            const float mu = M[o], be = Bb[o];
            float vmem = 0.f;
            for (int t = 0; t < TT; ++t) {
                float y = __fadd_rn(__fmul_rn(__fsub_rn(dots[t], mu), inv), be);
                vmem = __fadd_rn(vmem, __fmul_rn(__fsub_rn(y, vmem), 0.5f));
                int s = (vmem >= 0.5f);
                S[((size_t)((t * BB + b_) * NN) + n) * CC + o] = (unsigned char)s;
                if (s) vmem = 0.f;
            }
        }
        __syncthreads();
    }
}

// ---------------------------------------------------------------------------
// Kernel 3: v spikes [t,b,n,c] u8 -> f32 out [t,b,h,n,d] (coalesced float4)
// ---------------------------------------------------------------------------
__global__ __launch_bounds__(256) void k_vout(const unsigned char* __restrict__ vs,
                                              float* __restrict__ vout) {
    int e = blockIdx.x * 256 + threadIdx.x;
    int d4 = e % 12;
    int r = e / 12;
    int n = r & 255;
    r >>= 8;
    int h = r & 7;
    int tb = r >> 3;
    uchar4 u = *(const uchar4*)&vs[((size_t)tb * NN + n) * CC + h * HD + d4 * 4];
    float4 o = {(float)u.x, (float)u.y, (float)u.z, (float)u.w};
    *(float4*)&vout[(((size_t)tb * HEADS + h) * NN + n) * HD + d4 * 4] = o;
}

// ---------------------------------------------------------------------------
// Kernel 4: kvsum[t,b,c] = sum_n k*v  (exact integer)
// ---------------------------------------------------------------------------
__global__ __launch_bounds__(256) void k_kvsum(const unsigned char* __restrict__ ks,
                                               const unsigned char* __restrict__ vs,
                                               int* __restrict__ kvsum) {
    __shared__ int P[5][CC];
    const int tb = blockIdx.x, tid = threadIdx.x;
    if (tid < 240) {
        int c8 = tid % 48, sl = tid / 48;
        int a[8] = {0, 0, 0, 0, 0, 0, 0, 0};
        for (int n = sl; n < NN; n += 5) {
            u64 kk = *(const u64*)&ks[((size_t)tb * NN + n) * CC + c8 * 8];
            u64 vvv = *(const u64*)&vs[((size_t)tb * NN + n) * CC + c8 * 8];
            u64 u = kk & vvv;
#pragma unroll
            for (int j = 0; j < 8; ++j) a[j] += (int)((u >> (8 * j)) & 1);
        }
#pragma unroll
        for (int j = 0; j < 8; ++j) P[sl][c8 * 8 + j] = a[j];
    }
    __syncthreads();
    for (int c = tid; c < CC; c += 256) {
        kvsum[(size_t)tb * CC + c] = P[0][c] + P[1][c] + P[2][c] + P[3][c] + P[4][c];
    }
}

// ---------------------------------------------------------------------------
// Kernel 5: talking heads + LIF, fp32 np-order
// ---------------------------------------------------------------------------
__global__ __launch_bounds__(384) void k_thlif(const int* __restrict__ kvsum,
                                               const float* __restrict__ th,
                                               unsigned char* __restrict__ kvm) {
    __shared__ int kv0[TT][CC];
    const int b_ = blockIdx.x, c = threadIdx.x;
#pragma unroll
    for (int t = 0; t < TT; ++t) kv0[t][c] = kvsum[(size_t)(t * BB + b_) * CC + c];
    __syncthreads();
    const int ho = c / HD, d = c % HD;
    float vmem = 0.f;
#pragma unroll
    for (int t = 0; t < TT; ++t) {
        float s = 0.f;
#pragma unroll
        for (int h = 0; h < HEADS; ++h)
            s = __fadd_rn(s, __fmul_rn(th[ho * HEADS + h], (float)kv0[t][h * HD + d]));
        vmem = __fadd_rn(vmem, __fmul_rn(__fsub_rn(s, vmem), 0.5f));
        int sp = (vmem >= 0.5f);
        kvm[(size_t)(t * BB + b_) * CC + c] = (unsigned char)sp;
        if (sp) vmem = 0.f;
    }
}

// ---------------------------------------------------------------------------
// Kernel 6: proj GEMM, 2-plane (round(w*2^15)) i8 path on q & kvmask;
// fp32 np-order epilogue: +bias, BN, +identity -> f32 out [t,b,c,n]
// ---------------------------------------------------------------------------
__global__ __launch_bounds__(256, 3) void k_proj_i8(
    const unsigned char* __restrict__ qs, const unsigned char* __restrict__ kvm,
    const signed char* __restrict__ wq, const float* __restrict__ pbias,
    const float* __restrict__ gg, const float* __restrict__ bbp,
    const float* __restrict__ mmp, const float* __restrict__ vvp,
    const float* __restrict__ xin, float* __restrict__ out) {
    __shared__ unsigned char S[4][32][SROW];
    const int b_ = blockIdx.x, ob = blockIdx.y * 64, nb = blockIdx.z * 32;
    const int tid = threadIdx.x, lane = tid & 63, w = tid >> 6;
    const int lo16 = lane & 15, hi4 = lane >> 4;

    // stage full-K (q & kvmask) tile once (pow2 map)
    {
        const int sl3 = tid & 7;
#pragma unroll
        for (int i = 0; i < 4; ++i) {
            int row = i * 32 + (tid >> 3);             // t = row>>5, n = row&31
            int t = row >> 5, n = row & 31;
            const unsigned char* srcq = &qs[((size_t)((t * BB + b_) * NN) + nb + n) * CC];
            const unsigned char* srcm = &kvm[(size_t)((t * BB + b_) * CC)];
            unsigned char* dst = &S[0][0][0] + row * SROW;
#pragma unroll
            for (int j = 0; j < 3; ++j) {
                int so = (sl3 + 8 * j) * 16;
                i32x4 qv = *(const i32x4*)(srcq + so);
                i32x4 mv = *(const i32x4*)(srcm + so);
                *(i32x4*)(dst + so) = qv & mv;
            }
        }
    }
    __syncthreads();

    i32x4 acc[2][4][2];
#pragma unroll
    for (int p = 0; p < 2; ++p)
#pragma unroll
        for (int t = 0; t < 4; ++t)
#pragma unroll
            for (int nf = 0; nf < 2; ++nf) acc[p][t][nf] = (i32x4){0, 0, 0, 0};

    const signed char* wptr = wq + (size_t)(ob + w * 16 + lo16) * CC + hi4 * 16;
    const unsigned char* sbase = &S[0][lo16][hi4 * 16];
    i32x4 aw0 = *(const i32x4*)&wptr[0 * CCC];
    i32x4 aw1 = *(const i32x4*)&wptr[1 * CCC];

#pragma unroll
    for (int s = 0; s < 6; ++s) {
        i32x4 nw0, nw1;
        if (s < 5) {
            nw0 = *(const i32x4*)&wptr[0 * CCC + (s + 1) * 64];
            nw1 = *(const i32x4*)&wptr[1 * CCC + (s + 1) * 64];
        }
        __builtin_amdgcn_s_setprio(1);
#pragma unroll
        for (int t = 0; t < 4; ++t)
#pragma unroll
            for (int nf = 0; nf < 2; ++nf) {
                i32x4 bfr = *(const i32x4*)&sbase[(t * 32 + nf * 16) * SROW + s * 64];
                acc[0][t][nf] = __builtin_amdgcn_mfma_i32_16x16x64_i8(aw0, bfr, acc[0][t][nf], 0, 0, 0);
                acc[1][t][nf] = __builtin_amdgcn_mfma_i32_16x16x64_i8(aw1, bfr, acc[1][t][nf], 0, 0, 0);
            }
        __builtin_amdgcn_s_setprio(0);
        if (s < 5) { aw0 = nw0; aw1 = nw1; }
    }

#pragma unroll
    for (int r = 0; r < 4; ++r) {
        const int o = ob + w * 16 + hi4 * 4 + r;
        const float inv = __fdiv_rn(gg[o], __fsqrt_rn(__fadd_rn(vvp[o], 1e-5f)));
        const float mu = mmp[o], be = bbp[o], pb = pbias[o];
#pragma unroll
        for (int nf = 0; nf < 2; ++nf) {
#pragma unroll
            for (int t = 0; t < 4; ++t) {
                float dotf = recomb2(acc[0][t][nf][r], acc[1][t][nf][r]);
                size_t idx = ((size_t)((t * BB + b_) * CC) + o) * NN + nb + nf * 16 + lo16;
                float y = __fadd_rn(__fmul_rn(__fsub_rn(__fadd_rn(dotf, pb), mu), inv), be);
                out[idx] = __fadd_rn(y, xin[idx]);
            }
        }
    }
}

// ---------------------------------------------------------------------------
extern "C" void kernel_launch(void* const* d_in, const int* in_sizes, int n_in,
                              void* d_out, int out_size, void* d_ws, size_t ws_size,
                              hipStream_t stream) {
    const float* x    = (const float*)d_in[0];
    const float* q_w  = (const float*)d_in[1];
    const float* k_w  = (const float*)d_in[2];
    const float* v_w  = (const float*)d_in[3];
    const float* q_g  = (const float*)d_in[4];
    const float* q_b  = (const float*)d_in[5];
    const float* q_m  = (const float*)d_in[6];
    const float* q_v  = (const float*)d_in[7];
    const float* k_g  = (const float*)d_in[8];
    const float* k_b  = (const float*)d_in[9];
    const float* k_m  = (const float*)d_in[10];
    const float* k_v  = (const float*)d_in[11];
    const float* v_g  = (const float*)d_in[12];
    const float* v_b  = (const float*)d_in[13];
    const float* v_m  = (const float*)d_in[14];
    const float* v_v  = (const float*)d_in[15];
    const float* p_g  = (const float*)d_in[16];
    const float* p_b  = (const float*)d_in[17];
    const float* p_m  = (const float*)d_in[18];
    const float* p_v  = (const float*)d_in[19];
    const float* th_w = (const float*)d_in[20];
    const float* pr_w = (const float*)d_in[21];
    const float* pr_b = (const float*)d_in[22];

    float* out  = (float*)d_out;
    float* vout = out + (size_t)TBCN;

    unsigned char* ws  = (unsigned char*)d_ws;
    unsigned char* xs  = ws;
    unsigned char* qs  = ws + (size_t)TBCN;
    unsigned char* ks2 = ws + (size_t)2 * TBCN;
    unsigned char* vs2 = ws + (size_t)3 * TBCN;
    signed char* wq    = (signed char*)(ws + (size_t)4 * TBCN);          // 4 mats * 3*CCC
    int* kvsum         = (int*)(ws + (size_t)4 * TBCN + 12ull * CCC);
    unsigned char* kvm = (unsigned char*)(kvsum + TT * BB * CC);
    unsigned* fcnt     = (unsigned*)(kvm + (size_t)TT * BB * CC + 64);
    unsigned* flist    = fcnt + 16;

    k_wsplit<<<(4 * CCC) / 256, 256, 0, stream>>>(q_w, k_w, v_w, pr_w, wq, fcnt);
    k_lif_x<<<dim3(BB, CC / 64, NN / 64), 256, 0, stream>>>(x, xs);

    // fused q/k/v branches: grid.y = mat*6 + ob_tile
    k_branch_i8<<<dim3(BB, 18, NN / 32), 256, 0, stream>>>(
        xs, wq,
        q_g, q_b, q_m, q_v,
        k_g, k_b, k_m, k_v,
        v_g, v_b, v_m, v_v,
        qs, ks2, vs2, fcnt, flist);

    k_fixup<<<2048, 256, 0, stream>>>(xs, q_w, k_w, v_w,
                                      q_g, q_b, q_m, q_v,
                                      k_g, k_b, k_m, k_v,
                                      v_g, v_b, v_m, v_v,
                                      qs, ks2, vs2, fcnt, flist);

    k_vout<<<(TBCN / 4) / 256, 256, 0, stream>>>(vs2, vout);
    k_kvsum<<<TT * BB, 256, 0, stream>>>(ks2, vs2, kvsum);
    k_thlif<<<BB, CC, 0, stream>>>(kvsum, th_w, kvm);

    k_proj_i8<<<dim3(BB, CC / 64, NN / 32), 256, 0, stream>>>(
        qs, kvm, wq + 3ull * 3 * CCC, pr_b,
        p_g, p_b, p_m, p_v, x, out);
}